// Round 4
// baseline (1832.790 us; speedup 1.0000x reference)
//
#include <hip/hip_runtime.h>

// SoftFAPELoss: B=8, N=M=4096, D=3.
// Grid 1024 blocks x 512 thr (8 waves). Block = (b, rowgroup of 256 rows,
// 1/8th of M = 512 q-points). Block stages its 512 transformed+prescaled
// q's into 8 KB LDS; each wave scans a 64-q slice; lane owns 4 rows
// (rows 4*lane..4*lane+3), so one ds_read_b128 broadcast feeds 256 pairs
// and 4 independent exp chains. Per pair: dc = c*|p-q|^2 via expanded
// square (3 fma + 1 add), w = exp2(-dc) (arg <= 0: no overflow),
// L += w, S = fma(w,dc,S). Per-row partials merged in LDS across the 8
// waves, then float-atomicAdd into global Lg/Sg (8 contributors/row).
// Final kernel: wd = S/L per row (cold full-recompute fallback if L
// underflowed), mean, unscale by 1/c = T*ln2.

#define B_    8
#define N_    4096
#define M_    4096
#define NWAVE 8
#define BLOCK (NWAVE * 64)        // 512
#define ROWS  256                 // rows per block (4 per lane)
#define MSPL  8                   // M split across blocks
#define QCH   (M_ / MSPL)         // 512 q per block
#define WQ    (QCH / NWAVE)       // 64 q per wave
#define LOG2E 1.4426950408889634f
#define LN2   0.6931471805599453f

__global__ __launch_bounds__(BLOCK, 8) void softfape_main(
    const float* __restrict__ X_pred, const float* __restrict__ X_true,
    const float* __restrict__ R_pred, const float* __restrict__ t_pred,
    const float* __restrict__ R_true, const float* __restrict__ t_true,
    const float* __restrict__ temp,
    float* __restrict__ Lg, float* __restrict__ Sg)
{
    __shared__ float4 Q[QCH];            // 8 KB
    __shared__ float  Lp[NWAVE][ROWS];   // 8 KB
    __shared__ float  Sp[NWAVE][ROWS];   // 8 KB

    const int tid  = threadIdx.x;
    const int wave = tid >> 6;
    const int lane = tid & 63;
    const int x    = blockIdx.x;
    const int ms   = x & 7;
    const int rg   = (x >> 3) & 15;
    const int b    = x >> 7;

    const float T   = temp[0];
    const float c   = LOG2E / T;
    const float m2c = -2.0f * c;

    // ---- stage 512 transformed+prescaled q's (threads 0..255, 2 each) ----
    if (tid < QCH / 2) {
        const float g00 = R_true[b*9+0], g01 = R_true[b*9+1], g02 = R_true[b*9+2];
        const float g10 = R_true[b*9+3], g11 = R_true[b*9+4], g12 = R_true[b*9+5];
        const float g20 = R_true[b*9+6], g21 = R_true[b*9+7], g22 = R_true[b*9+8];
        const float u0  = t_true[b*3+0], u1 = t_true[b*3+1], u2 = t_true[b*3+2];
        const float2* xt = (const float2*)(X_true + ((size_t)b * M_ + ms * QCH) * 3);
        const float2 f0 = xt[3*tid+0], f1 = xt[3*tid+1], f2 = xt[3*tid+2];
        {
            const float y0 = fmaf(g00, f0.x, fmaf(g01, f0.y, fmaf(g02, f1.x, u0)));
            const float y1 = fmaf(g10, f0.x, fmaf(g11, f0.y, fmaf(g12, f1.x, u1)));
            const float y2 = fmaf(g20, f0.x, fmaf(g21, f0.y, fmaf(g22, f1.x, u2)));
            const float nn = fmaf(y0, y0, fmaf(y1, y1, y2 * y2));
            Q[2*tid]   = make_float4(m2c*y0, m2c*y1, m2c*y2, c*nn);
        }
        {
            const float y0 = fmaf(g00, f1.y, fmaf(g01, f2.x, fmaf(g02, f2.y, u0)));
            const float y1 = fmaf(g10, f1.y, fmaf(g11, f2.x, fmaf(g12, f2.y, u1)));
            const float y2 = fmaf(g20, f1.y, fmaf(g21, f2.x, fmaf(g22, f2.y, u2)));
            const float nn = fmaf(y0, y0, fmaf(y1, y1, y2 * y2));
            Q[2*tid+1] = make_float4(m2c*y0, m2c*y1, m2c*y2, c*nn);
        }
    }

    // ---- my 4 rows: transformed pred points + prescaled squared norms ----
    float px[4], py[4], pz[4], pw[4];
    {
        const float h00 = R_pred[b*9+0], h01 = R_pred[b*9+1], h02 = R_pred[b*9+2];
        const float h10 = R_pred[b*9+3], h11 = R_pred[b*9+4], h12 = R_pred[b*9+5];
        const float h20 = R_pred[b*9+6], h21 = R_pred[b*9+7], h22 = R_pred[b*9+8];
        const float v0 = t_pred[b*3+0], v1 = t_pred[b*3+1], v2 = t_pred[b*3+2];
        const float4* xp = (const float4*)(X_pred + ((size_t)b * N_ + rg * ROWS + lane * 4) * 3);
        const float4 a0 = xp[0], a1 = xp[1], a2 = xp[2];
        const float rx[4] = {a0.x, a0.w, a1.z, a2.y};
        const float ry[4] = {a0.y, a1.x, a1.w, a2.z};
        const float rz[4] = {a0.z, a1.y, a2.x, a2.w};
        #pragma unroll
        for (int r = 0; r < 4; ++r) {
            px[r] = fmaf(h00, rx[r], fmaf(h01, ry[r], fmaf(h02, rz[r], v0)));
            py[r] = fmaf(h10, rx[r], fmaf(h11, ry[r], fmaf(h12, rz[r], v1)));
            pz[r] = fmaf(h20, rx[r], fmaf(h21, ry[r], fmaf(h22, rz[r], v2)));
            pw[r] = c * fmaf(px[r], px[r], fmaf(py[r], py[r], pz[r] * pz[r]));
        }
    }

    __syncthreads();

    // ---- hot loop: 64 q's x 4 rows per lane ----
    float L[4] = {0.f, 0.f, 0.f, 0.f};
    float S[4] = {0.f, 0.f, 0.f, 0.f};
    const float4* __restrict__ Qw = Q + wave * WQ;
    #pragma unroll 2
    for (int k = 0; k < WQ; ++k) {
        const float4 q = Qw[k];   // ds_read_b128, wave-uniform broadcast
        #pragma unroll
        for (int r = 0; r < 4; ++r) {
            const float d = fmaf(q.x, px[r], fmaf(q.y, py[r], fmaf(q.z, pz[r], q.w))) + pw[r];
            const float w = __builtin_amdgcn_exp2f(-d);
            L[r] += w;
            S[r] = fmaf(w, d, S[r]);
        }
    }

    #pragma unroll
    for (int r = 0; r < 4; ++r) {
        Lp[wave][4*lane + r] = L[r];
        Sp[wave][4*lane + r] = S[r];
    }
    __syncthreads();

    // ---- merge 8 wave-partials per row, atomic into global per-row sums ----
    if (tid < ROWS) {
        float Lr = 0.0f, Sr = 0.0f;
        #pragma unroll
        for (int w2 = 0; w2 < NWAVE; ++w2) { Lr += Lp[w2][tid]; Sr += Sp[w2][tid]; }
        const int grow = b * N_ + rg * ROWS + tid;
        atomicAdd(&Lg[grow], Lr);
        atomicAdd(&Sg[grow], Sr);
    }
}

__global__ __launch_bounds__(512) void softfape_final(
    const float* __restrict__ Lg, const float* __restrict__ Sg,
    const float* __restrict__ X_pred, const float* __restrict__ X_true,
    const float* __restrict__ R_pred, const float* __restrict__ t_pred,
    const float* __restrict__ R_true, const float* __restrict__ t_true,
    const float* __restrict__ temp, float* __restrict__ out)
{
    __shared__ float wsum[8];
    const int tid = threadIdx.x;
    const int r   = blockIdx.x * 512 + tid;
    const float T = temp[0];
    const float c = LOG2E / T;

    float wd;
    const float Lr = Lg[r], Sr = Sg[r];
    if (Lr > 1e-30f) {
        wd = Sr / Lr;
    } else {
        // cold fallback: recompute this row with max-shift (never in practice)
        const int b = r >> 12;
        float p0, p1, p2;
        {
            const float* xp = X_pred + (size_t)r * 3;
            const float x = xp[0], y = xp[1], z = xp[2];
            p0 = fmaf(R_pred[b*9+0], x, fmaf(R_pred[b*9+1], y, fmaf(R_pred[b*9+2], z, t_pred[b*3+0])));
            p1 = fmaf(R_pred[b*9+3], x, fmaf(R_pred[b*9+4], y, fmaf(R_pred[b*9+5], z, t_pred[b*3+1])));
            p2 = fmaf(R_pred[b*9+6], x, fmaf(R_pred[b*9+7], y, fmaf(R_pred[b*9+8], z, t_pred[b*3+2])));
        }
        float mind = 3.0e38f;
        for (int pass = 0; pass < 2; ++pass) {
            float Lacc = 0.0f, Sacc = 0.0f;
            for (int m = 0; m < M_; ++m) {
                const float* xt = X_true + ((size_t)b * M_ + m) * 3;
                const float x = xt[0], y = xt[1], z = xt[2];
                const float y0 = fmaf(R_true[b*9+0], x, fmaf(R_true[b*9+1], y, fmaf(R_true[b*9+2], z, t_true[b*3+0])));
                const float y1 = fmaf(R_true[b*9+3], x, fmaf(R_true[b*9+4], y, fmaf(R_true[b*9+5], z, t_true[b*3+1])));
                const float y2 = fmaf(R_true[b*9+6], x, fmaf(R_true[b*9+7], y, fmaf(R_true[b*9+8], z, t_true[b*3+2])));
                const float dx = y0 - p0, dy = y1 - p1, dz = y2 - p2;
                const float d = c * fmaf(dx, dx, fmaf(dy, dy, dz * dz));
                if (pass == 0) { mind = fminf(mind, d); }
                else {
                    const float w = __builtin_amdgcn_exp2f(mind - d);
                    Lacc += w; Sacc = fmaf(w, d, Sacc);
                }
            }
            if (pass == 1) wd = Sacc / Lacc;
        }
    }

    // block reduce 512 values -> 1 atomic
    float v = wd;
    v += __shfl_xor(v, 1);  v += __shfl_xor(v, 2);  v += __shfl_xor(v, 4);
    v += __shfl_xor(v, 8);  v += __shfl_xor(v, 16); v += __shfl_xor(v, 32);
    if ((tid & 63) == 0) wsum[tid >> 6] = v;
    __syncthreads();
    if (tid == 0) {
        float s = 0.0f;
        #pragma unroll
        for (int i = 0; i < 8; ++i) s += wsum[i];
        const float scale = T * LN2 / ((float)B_ * (float)N_);  // 1/c, mean
        atomicAdd(out, s * scale);
    }
}

extern "C" void kernel_launch(void* const* d_in, const int* in_sizes, int n_in,
                              void* d_out, int out_size, void* d_ws, size_t ws_size,
                              hipStream_t stream) {
    const float* X_pred = (const float*)d_in[0];
    const float* X_true = (const float*)d_in[1];
    const float* R_pred = (const float*)d_in[2];
    const float* t_pred = (const float*)d_in[3];
    const float* R_true = (const float*)d_in[4];
    const float* t_true = (const float*)d_in[5];
    const float* temp   = (const float*)d_in[6];
    float* out = (float*)d_out;

    float* Lg = (float*)d_ws;                    // B*N floats
    float* Sg = Lg + (size_t)B_ * N_;            // B*N floats

    hipMemsetAsync(d_ws, 0, (size_t)B_ * N_ * 2 * sizeof(float), stream);
    hipMemsetAsync(out, 0, sizeof(float), stream);

    softfape_main<<<dim3(B_ * 16 * MSPL), BLOCK, 0, stream>>>(
        X_pred, X_true, R_pred, t_pred, R_true, t_true, temp, Lg, Sg);

    softfape_final<<<dim3((B_ * N_) / 512), 512, 0, stream>>>(
        Lg, Sg, X_pred, X_true, R_pred, t_pred, R_true, t_true, temp, out);
}

// Round 5
// 222.208 us; speedup vs baseline: 8.2481x; 8.2481x over previous
//
#include <hip/hip_runtime.h>

// SoftFAPELoss: B=8, N=M=4096, D=3.
// softfape_main: grid 1024 x 512 thr (8 waves). Block = (b, 256-row group,
//   1/8th of M = 512 q). q's transformed+prescaled into 8 KB LDS; wave scans
//   a 64-q slice via wave-uniform ds_read_b128 broadcast; lane owns 4 rows.
//   Per pair: A = c(|q|^2 - 2 q.p) via 3 fma; arg = (K - c|p|^2) - A = K - d
//   (1 sub); w = exp2(arg) (K=100 shift: underflow needs min dist^2 > ~14);
//   L += w; Sarg = fma(w, arg, Sarg). wd = K - Sarg/L (shift-invariant).
//   Wave partials merged in LDS, atomicAdd into global Lg/Sg.
// softfape_finalize: per row wd = K - S/L; rows with L < 1e-28 appended to a
//   bad list (expected ~0..50); block-reduced atomicAdd into out.
// softfape_repair: 64 blocks grid-stride the bad list; 256 threads per row do
//   exact two-pass (min, shifted sum) recompute; atomicAdd contribution.

#define B_    8
#define N_    4096
#define M_    4096
#define NWAVE 8
#define BLOCK (NWAVE * 64)        // 512
#define ROWS  256                 // rows per block (4 per lane)
#define MSPL  8                   // M split across blocks
#define QCH   (M_ / MSPL)         // 512 q per block
#define WQ    (QCH / NWAVE)       // 64 q per wave
#define KSH   100.0f
#define LOG2E 1.4426950408889634f
#define LN2   0.6931471805599453f

__global__ __launch_bounds__(BLOCK, 8) void softfape_main(
    const float* __restrict__ X_pred, const float* __restrict__ X_true,
    const float* __restrict__ R_pred, const float* __restrict__ t_pred,
    const float* __restrict__ R_true, const float* __restrict__ t_true,
    const float* __restrict__ temp,
    float* __restrict__ Lg, float* __restrict__ Sg)
{
    __shared__ float4 Q[QCH];            // 8 KB
    __shared__ float  Lp[NWAVE][ROWS];   // 8 KB
    __shared__ float  Sp[NWAVE][ROWS];   // 8 KB

    const int tid  = threadIdx.x;
    const int wave = tid >> 6;
    const int lane = tid & 63;
    const int x    = blockIdx.x;
    const int ms   = x & 7;
    const int rg   = (x >> 3) & 15;
    const int b    = x >> 7;

    const float T   = temp[0];
    const float c   = LOG2E / T;
    const float m2c = -2.0f * c;

    // ---- stage 512 transformed+prescaled q's (threads 0..255, 2 each) ----
    if (tid < QCH / 2) {
        const float g00 = R_true[b*9+0], g01 = R_true[b*9+1], g02 = R_true[b*9+2];
        const float g10 = R_true[b*9+3], g11 = R_true[b*9+4], g12 = R_true[b*9+5];
        const float g20 = R_true[b*9+6], g21 = R_true[b*9+7], g22 = R_true[b*9+8];
        const float u0  = t_true[b*3+0], u1 = t_true[b*3+1], u2 = t_true[b*3+2];
        const float2* xt = (const float2*)(X_true + ((size_t)b * M_ + ms * QCH) * 3);
        const float2 f0 = xt[3*tid+0], f1 = xt[3*tid+1], f2 = xt[3*tid+2];
        {
            const float y0 = fmaf(g00, f0.x, fmaf(g01, f0.y, fmaf(g02, f1.x, u0)));
            const float y1 = fmaf(g10, f0.x, fmaf(g11, f0.y, fmaf(g12, f1.x, u1)));
            const float y2 = fmaf(g20, f0.x, fmaf(g21, f0.y, fmaf(g22, f1.x, u2)));
            const float nn = fmaf(y0, y0, fmaf(y1, y1, y2 * y2));
            Q[2*tid]   = make_float4(m2c*y0, m2c*y1, m2c*y2, c*nn);
        }
        {
            const float y0 = fmaf(g00, f1.y, fmaf(g01, f2.x, fmaf(g02, f2.y, u0)));
            const float y1 = fmaf(g10, f1.y, fmaf(g11, f2.x, fmaf(g12, f2.y, u1)));
            const float y2 = fmaf(g20, f1.y, fmaf(g21, f2.x, fmaf(g22, f2.y, u2)));
            const float nn = fmaf(y0, y0, fmaf(y1, y1, y2 * y2));
            Q[2*tid+1] = make_float4(m2c*y0, m2c*y1, m2c*y2, c*nn);
        }
    }

    // ---- my 4 rows: transformed pred points, pwK = K - c|p|^2 ----
    float px[4], py[4], pz[4], pwK[4];
    {
        const float h00 = R_pred[b*9+0], h01 = R_pred[b*9+1], h02 = R_pred[b*9+2];
        const float h10 = R_pred[b*9+3], h11 = R_pred[b*9+4], h12 = R_pred[b*9+5];
        const float h20 = R_pred[b*9+6], h21 = R_pred[b*9+7], h22 = R_pred[b*9+8];
        const float v0 = t_pred[b*3+0], v1 = t_pred[b*3+1], v2 = t_pred[b*3+2];
        const float4* xp = (const float4*)(X_pred + ((size_t)b * N_ + rg * ROWS + lane * 4) * 3);
        const float4 a0 = xp[0], a1 = xp[1], a2 = xp[2];
        const float rx[4] = {a0.x, a0.w, a1.z, a2.y};
        const float ry[4] = {a0.y, a1.x, a1.w, a2.z};
        const float rz[4] = {a0.z, a1.y, a2.x, a2.w};
        #pragma unroll
        for (int r = 0; r < 4; ++r) {
            px[r] = fmaf(h00, rx[r], fmaf(h01, ry[r], fmaf(h02, rz[r], v0)));
            py[r] = fmaf(h10, rx[r], fmaf(h11, ry[r], fmaf(h12, rz[r], v1)));
            pz[r] = fmaf(h20, rx[r], fmaf(h21, ry[r], fmaf(h22, rz[r], v2)));
            pwK[r] = KSH - c * fmaf(px[r], px[r], fmaf(py[r], py[r], pz[r] * pz[r]));
        }
    }

    __syncthreads();

    // ---- hot loop: 64 q's x 4 rows per lane ----
    float L[4] = {0.f, 0.f, 0.f, 0.f};
    float S[4] = {0.f, 0.f, 0.f, 0.f};
    const float4* __restrict__ Qw = Q + wave * WQ;
    #pragma unroll 4
    for (int k = 0; k < WQ; ++k) {
        const float4 q = Qw[k];   // ds_read_b128, wave-uniform broadcast
        #pragma unroll
        for (int r = 0; r < 4; ++r) {
            const float A   = fmaf(q.x, px[r], fmaf(q.y, py[r], fmaf(q.z, pz[r], q.w)));
            const float arg = pwK[r] - A;                 // = K - c*dist^2
            const float w   = __builtin_amdgcn_exp2f(arg);
            L[r] += w;
            S[r] = fmaf(w, arg, S[r]);
        }
    }

    #pragma unroll
    for (int r = 0; r < 4; ++r) {
        Lp[wave][4*lane + r] = L[r];
        Sp[wave][4*lane + r] = S[r];
    }
    __syncthreads();

    // ---- merge 8 wave-partials per row, atomic into global per-row sums ----
    if (tid < ROWS) {
        float Lr = 0.0f, Sr = 0.0f;
        #pragma unroll
        for (int w2 = 0; w2 < NWAVE; ++w2) { Lr += Lp[w2][tid]; Sr += Sp[w2][tid]; }
        const int grow = b * N_ + rg * ROWS + tid;
        atomicAdd(&Lg[grow], Lr);
        atomicAdd(&Sg[grow], Sr);
    }
}

__global__ __launch_bounds__(256) void softfape_finalize(
    const float* __restrict__ Lg, const float* __restrict__ Sg,
    const float* __restrict__ temp,
    int* __restrict__ bad_cnt, int* __restrict__ bad_rows,
    float* __restrict__ out)
{
    __shared__ float ws4[4];
    const int tid = threadIdx.x;
    const int row = blockIdx.x * 256 + tid;

    const float Lr = Lg[row], Sr = Sg[row];
    float wd = 0.0f;
    if (Lr >= 1e-28f) {
        wd = KSH - Sr / Lr;          // = c * weighted_distance(row)
    } else {
        const int s = atomicAdd(bad_cnt, 1);
        bad_rows[s] = row;           // repaired exactly later; contributes 0 here
    }

    wd += __shfl_xor(wd, 1);  wd += __shfl_xor(wd, 2);  wd += __shfl_xor(wd, 4);
    wd += __shfl_xor(wd, 8);  wd += __shfl_xor(wd, 16); wd += __shfl_xor(wd, 32);
    if ((tid & 63) == 0) ws4[tid >> 6] = wd;
    __syncthreads();
    if (tid == 0) {
        const float s = ws4[0] + ws4[1] + ws4[2] + ws4[3];
        const float scale = temp[0] * LN2 / ((float)B_ * (float)N_);  // 1/c, mean
        atomicAdd(out, s * scale);
    }
}

__global__ __launch_bounds__(256) void softfape_repair(
    const int* __restrict__ bad_cnt, const int* __restrict__ bad_rows,
    const float* __restrict__ X_pred, const float* __restrict__ X_true,
    const float* __restrict__ R_pred, const float* __restrict__ t_pred,
    const float* __restrict__ R_true, const float* __restrict__ t_true,
    const float* __restrict__ temp, float* __restrict__ out)
{
    __shared__ float redL[256];
    __shared__ float redS[256];

    const int cnt = *bad_cnt;
    const int tid = threadIdx.x;
    const float T = temp[0];
    const float c = LOG2E / T;

    for (int idx = blockIdx.x; idx < cnt; idx += gridDim.x) {
        const int row = bad_rows[idx];
        const int b   = row >> 12;

        // p (same for all threads; served from cache)
        const float* xp = X_pred + (size_t)row * 3;
        const float xx = xp[0], yy = xp[1], zz = xp[2];
        const float p0 = fmaf(R_pred[b*9+0], xx, fmaf(R_pred[b*9+1], yy, fmaf(R_pred[b*9+2], zz, t_pred[b*3+0])));
        const float p1 = fmaf(R_pred[b*9+3], xx, fmaf(R_pred[b*9+4], yy, fmaf(R_pred[b*9+5], zz, t_pred[b*3+1])));
        const float p2 = fmaf(R_pred[b*9+6], xx, fmaf(R_pred[b*9+7], yy, fmaf(R_pred[b*9+8], zz, t_pred[b*3+2])));

        const float g00 = R_true[b*9+0], g01 = R_true[b*9+1], g02 = R_true[b*9+2];
        const float g10 = R_true[b*9+3], g11 = R_true[b*9+4], g12 = R_true[b*9+5];
        const float g20 = R_true[b*9+6], g21 = R_true[b*9+7], g22 = R_true[b*9+8];
        const float u0  = t_true[b*3+0], u1 = t_true[b*3+1], u2 = t_true[b*3+2];

        // pass 1: min d over this thread's strided subset
        float mn = 3.0e38f;
        for (int m = tid; m < M_; m += 256) {
            const float* xt = X_true + ((size_t)b * M_ + m) * 3;
            const float x = xt[0], y = xt[1], z = xt[2];
            const float y0 = fmaf(g00, x, fmaf(g01, y, fmaf(g02, z, u0)));
            const float y1 = fmaf(g10, x, fmaf(g11, y, fmaf(g12, z, u1)));
            const float y2 = fmaf(g20, x, fmaf(g21, y, fmaf(g22, z, u2)));
            const float dx = y0 - p0, dy = y1 - p1, dz = y2 - p2;
            mn = fminf(mn, c * fmaf(dx, dx, fmaf(dy, dy, dz * dz)));
        }
        redL[tid] = mn;
        __syncthreads();
        for (int s2 = 128; s2 > 0; s2 >>= 1) {
            if (tid < s2) redL[tid] = fminf(redL[tid], redL[tid + s2]);
            __syncthreads();
        }
        const float sh = redL[0];
        __syncthreads();

        // pass 2: shifted sums
        float L = 0.0f, S = 0.0f;
        for (int m = tid; m < M_; m += 256) {
            const float* xt = X_true + ((size_t)b * M_ + m) * 3;
            const float x = xt[0], y = xt[1], z = xt[2];
            const float y0 = fmaf(g00, x, fmaf(g01, y, fmaf(g02, z, u0)));
            const float y1 = fmaf(g10, x, fmaf(g11, y, fmaf(g12, z, u1)));
            const float y2 = fmaf(g20, x, fmaf(g21, y, fmaf(g22, z, u2)));
            const float dx = y0 - p0, dy = y1 - p1, dz = y2 - p2;
            const float d = c * fmaf(dx, dx, fmaf(dy, dy, dz * dz));
            const float w = __builtin_amdgcn_exp2f(sh - d);  // min pair -> 1
            L += w;
            S = fmaf(w, d, S);
        }
        redL[tid] = L;
        redS[tid] = S;
        __syncthreads();
        for (int s2 = 128; s2 > 0; s2 >>= 1) {
            if (tid < s2) { redL[tid] += redL[tid + s2]; redS[tid] += redS[tid + s2]; }
            __syncthreads();
        }
        if (tid == 0) {
            const float scale = T * LN2 / ((float)B_ * (float)N_);
            atomicAdd(out, (redS[0] / redL[0]) * scale);
        }
        __syncthreads();
    }
}

extern "C" void kernel_launch(void* const* d_in, const int* in_sizes, int n_in,
                              void* d_out, int out_size, void* d_ws, size_t ws_size,
                              hipStream_t stream) {
    const float* X_pred = (const float*)d_in[0];
    const float* X_true = (const float*)d_in[1];
    const float* R_pred = (const float*)d_in[2];
    const float* t_pred = (const float*)d_in[3];
    const float* R_true = (const float*)d_in[4];
    const float* t_true = (const float*)d_in[5];
    const float* temp   = (const float*)d_in[6];
    float* out = (float*)d_out;

    float* Lg       = (float*)d_ws;                       // B*N floats
    float* Sg       = Lg + (size_t)B_ * N_;               // B*N floats
    int*   bad_cnt  = (int*)(Sg + (size_t)B_ * N_);       // 1 int
    int*   bad_rows = bad_cnt + 1;                        // up to B*N ints

    // zero Lg, Sg, bad_cnt (contiguous), and out
    hipMemsetAsync(d_ws, 0, (size_t)B_ * N_ * 2 * sizeof(float) + sizeof(int), stream);
    hipMemsetAsync(out, 0, sizeof(float), stream);

    softfape_main<<<dim3(B_ * 16 * MSPL), BLOCK, 0, stream>>>(
        X_pred, X_true, R_pred, t_pred, R_true, t_true, temp, Lg, Sg);

    softfape_finalize<<<dim3((B_ * N_) / 256), 256, 0, stream>>>(
        Lg, Sg, temp, bad_cnt, bad_rows, out);

    softfape_repair<<<dim3(64), 256, 0, stream>>>(
        bad_cnt, bad_rows, X_pred, X_true, R_pred, t_pred, R_true, t_true, temp, out);
}

// Round 6
// 115.583 us; speedup vs baseline: 15.8570x; 1.9225x over previous
//
#include <hip/hip_runtime.h>

// SoftFAPELoss: B=8, N=M=4096, D=3.
// Exact single-pass design: flash-style chunked online softmax. No repair.
// softfape_main: grid 1024 x 512 thr (8 waves). Block = (b, 256-row group,
//   1/8th of M = 512 q). q's transformed+prescaled into 8 KB LDS
//   (q.xyz = -2c*y, q.w = c*|y|^2); wave scans a 64-q slice via wave-uniform
//   ds_read_b128 broadcast; lane owns 4 rows. Per pair:
//     d  = c*|p-q|^2 = fma(q,p)x3 + pw            (4 VALU)
//     mN = min(m, d)                              (1)
//     sc = exp2(mN-m); w = exp2(mN-d)             (2 sub + 2 trans)
//     L  = fma(L, sc, w); S = fma(S, sc, w*d)     (3)
//   w <= 1 always, min term contributes exactly 1 -> L >= 1, never underflows.
//   8 wave-partials (m,L,S) merged in LDS with rescale, one float4 partial
//   per (row, ms) written to workspace.
// softfape_finalize: per row merge the 8 chunk partials (factors <= 1),
//   wd = S/L (= c * weighted_distance), block-reduce, atomicAdd with
//   scale T*ln2/(B*N).

#define B_    8
#define N_    4096
#define M_    4096
#define NWAVE 8
#define BLOCK (NWAVE * 64)        // 512
#define ROWS  256                 // rows per block (4 per lane)
#define MSPL  8                   // M split across blocks
#define QCH   (M_ / MSPL)         // 512 q per block
#define WQ    (QCH / NWAVE)       // 64 q per wave
#define LOG2E 1.4426950408889634f
#define LN2   0.6931471805599453f
#define BIGF  3.0e38f

__global__ __launch_bounds__(BLOCK, 8) void softfape_main(
    const float* __restrict__ X_pred, const float* __restrict__ X_true,
    const float* __restrict__ R_pred, const float* __restrict__ t_pred,
    const float* __restrict__ R_true, const float* __restrict__ t_true,
    const float* __restrict__ temp,
    float4* __restrict__ Pg)
{
    __shared__ float4 Q[QCH];            // 8 KB
    __shared__ float  Mp[NWAVE][ROWS];   // 8 KB
    __shared__ float  Lp[NWAVE][ROWS];   // 8 KB
    __shared__ float  Sp[NWAVE][ROWS];   // 8 KB

    const int tid  = threadIdx.x;
    const int wave = tid >> 6;
    const int lane = tid & 63;
    const int x    = blockIdx.x;
    const int ms   = x & 7;
    const int rg   = (x >> 3) & 15;
    const int b    = x >> 7;

    const float T   = temp[0];
    const float c   = LOG2E / T;
    const float m2c = -2.0f * c;

    // ---- stage 512 transformed+prescaled q's (threads 0..255, 2 each) ----
    if (tid < QCH / 2) {
        const float g00 = R_true[b*9+0], g01 = R_true[b*9+1], g02 = R_true[b*9+2];
        const float g10 = R_true[b*9+3], g11 = R_true[b*9+4], g12 = R_true[b*9+5];
        const float g20 = R_true[b*9+6], g21 = R_true[b*9+7], g22 = R_true[b*9+8];
        const float u0  = t_true[b*3+0], u1 = t_true[b*3+1], u2 = t_true[b*3+2];
        const float2* xt = (const float2*)(X_true + ((size_t)b * M_ + ms * QCH) * 3);
        const float2 f0 = xt[3*tid+0], f1 = xt[3*tid+1], f2 = xt[3*tid+2];
        {
            const float y0 = fmaf(g00, f0.x, fmaf(g01, f0.y, fmaf(g02, f1.x, u0)));
            const float y1 = fmaf(g10, f0.x, fmaf(g11, f0.y, fmaf(g12, f1.x, u1)));
            const float y2 = fmaf(g20, f0.x, fmaf(g21, f0.y, fmaf(g22, f1.x, u2)));
            const float nn = fmaf(y0, y0, fmaf(y1, y1, y2 * y2));
            Q[2*tid]   = make_float4(m2c*y0, m2c*y1, m2c*y2, c*nn);
        }
        {
            const float y0 = fmaf(g00, f1.y, fmaf(g01, f2.x, fmaf(g02, f2.y, u0)));
            const float y1 = fmaf(g10, f1.y, fmaf(g11, f2.x, fmaf(g12, f2.y, u1)));
            const float y2 = fmaf(g20, f1.y, fmaf(g21, f2.x, fmaf(g22, f2.y, u2)));
            const float nn = fmaf(y0, y0, fmaf(y1, y1, y2 * y2));
            Q[2*tid+1] = make_float4(m2c*y0, m2c*y1, m2c*y2, c*nn);
        }
    }

    // ---- my 4 rows: transformed pred points, pw = c*|p|^2 ----
    float px[4], py[4], pz[4], pw[4];
    {
        const float h00 = R_pred[b*9+0], h01 = R_pred[b*9+1], h02 = R_pred[b*9+2];
        const float h10 = R_pred[b*9+3], h11 = R_pred[b*9+4], h12 = R_pred[b*9+5];
        const float h20 = R_pred[b*9+6], h21 = R_pred[b*9+7], h22 = R_pred[b*9+8];
        const float v0 = t_pred[b*3+0], v1 = t_pred[b*3+1], v2 = t_pred[b*3+2];
        const float4* xp = (const float4*)(X_pred + ((size_t)b * N_ + rg * ROWS + lane * 4) * 3);
        const float4 a0 = xp[0], a1 = xp[1], a2 = xp[2];
        const float rx[4] = {a0.x, a0.w, a1.z, a2.y};
        const float ry[4] = {a0.y, a1.x, a1.w, a2.z};
        const float rz[4] = {a0.z, a1.y, a2.x, a2.w};
        #pragma unroll
        for (int r = 0; r < 4; ++r) {
            px[r] = fmaf(h00, rx[r], fmaf(h01, ry[r], fmaf(h02, rz[r], v0)));
            py[r] = fmaf(h10, rx[r], fmaf(h11, ry[r], fmaf(h12, rz[r], v1)));
            pz[r] = fmaf(h20, rx[r], fmaf(h21, ry[r], fmaf(h22, rz[r], v2)));
            pw[r] = c * fmaf(px[r], px[r], fmaf(py[r], py[r], pz[r] * pz[r]));
        }
    }

    __syncthreads();

    // ---- hot loop: 64 q's x 4 rows per lane, online-softmax accumulators ----
    float mr[4] = {BIGF, BIGF, BIGF, BIGF};
    float L[4]  = {0.f, 0.f, 0.f, 0.f};
    float S[4]  = {0.f, 0.f, 0.f, 0.f};
    const float4* __restrict__ Qw = Q + wave * WQ;
    #pragma unroll 2
    for (int k = 0; k < WQ; ++k) {
        const float4 q = Qw[k];   // ds_read_b128, wave-uniform broadcast
        #pragma unroll
        for (int r = 0; r < 4; ++r) {
            const float A  = fmaf(q.x, px[r], fmaf(q.y, py[r], fmaf(q.z, pz[r], q.w)));
            const float d  = A + pw[r];                    // c * dist^2
            const float mN = fminf(mr[r], d);
            const float sc = __builtin_amdgcn_exp2f(mN - mr[r]);  // <= 1
            const float w  = __builtin_amdgcn_exp2f(mN - d);      // <= 1
            L[r] = fmaf(L[r], sc, w);
            S[r] = fmaf(S[r], sc, w * d);
            mr[r] = mN;
        }
    }

    #pragma unroll
    for (int r = 0; r < 4; ++r) {
        Mp[wave][4*lane + r] = mr[r];
        Lp[wave][4*lane + r] = L[r];
        Sp[wave][4*lane + r] = S[r];
    }
    __syncthreads();

    // ---- merge 8 wave-partials per row with rescale; write chunk partial ----
    if (tid < ROWS) {
        float m = BIGF, Lr = 0.0f, Sr = 0.0f;
        #pragma unroll
        for (int w2 = 0; w2 < NWAVE; ++w2) {
            const float mw = Mp[w2][tid];
            const float lw = Lp[w2][tid];
            const float sw = Sp[w2][tid];
            const float mN = fminf(m, mw);
            const float e1 = __builtin_amdgcn_exp2f(mN - m);
            const float e2 = __builtin_amdgcn_exp2f(mN - mw);
            Lr = Lr * e1 + lw * e2;
            Sr = Sr * e1 + sw * e2;
            m = mN;
        }
        const size_t row = (size_t)b * N_ + rg * ROWS + tid;
        Pg[row * MSPL + ms] = make_float4(m, Lr, Sr, 0.0f);
    }
}

__global__ __launch_bounds__(256) void softfape_finalize(
    const float4* __restrict__ Pg, const float* __restrict__ temp,
    float* __restrict__ out)
{
    __shared__ float ws4[4];
    const int tid = threadIdx.x;
    const size_t row = (size_t)blockIdx.x * 256 + tid;

    float m = BIGF, L = 0.0f, S = 0.0f;
    #pragma unroll
    for (int i = 0; i < MSPL; ++i) {
        const float4 P = Pg[row * MSPL + i];
        const float mN = fminf(m, P.x);
        const float e1 = __builtin_amdgcn_exp2f(mN - m);
        const float e2 = __builtin_amdgcn_exp2f(mN - P.x);
        L = L * e1 + P.y * e2;
        S = S * e1 + P.z * e2;
        m = mN;
    }
    float wd = S / L;     // = c * weighted_distance(row); L >= 1 guaranteed

    wd += __shfl_xor(wd, 1);  wd += __shfl_xor(wd, 2);  wd += __shfl_xor(wd, 4);
    wd += __shfl_xor(wd, 8);  wd += __shfl_xor(wd, 16); wd += __shfl_xor(wd, 32);
    if ((tid & 63) == 0) ws4[tid >> 6] = wd;
    __syncthreads();
    if (tid == 0) {
        const float s = ws4[0] + ws4[1] + ws4[2] + ws4[3];
        const float scale = temp[0] * LN2 / ((float)B_ * (float)N_);  // 1/c, mean
        atomicAdd(out, s * scale);
    }
}

extern "C" void kernel_launch(void* const* d_in, const int* in_sizes, int n_in,
                              void* d_out, int out_size, void* d_ws, size_t ws_size,
                              hipStream_t stream) {
    const float* X_pred = (const float*)d_in[0];
    const float* X_true = (const float*)d_in[1];
    const float* R_pred = (const float*)d_in[2];
    const float* t_pred = (const float*)d_in[3];
    const float* R_true = (const float*)d_in[4];
    const float* t_true = (const float*)d_in[5];
    const float* temp   = (const float*)d_in[6];
    float* out = (float*)d_out;

    float4* Pg = (float4*)d_ws;   // B*N*MSPL float4 = 4 MB, fully overwritten

    hipMemsetAsync(out, 0, sizeof(float), stream);

    softfape_main<<<dim3(B_ * 16 * MSPL), BLOCK, 0, stream>>>(
        X_pred, X_true, R_pred, t_pred, R_true, t_true, temp, Pg);

    softfape_finalize<<<dim3((B_ * N_) / 256), 256, 0, stream>>>(Pg, temp, out);
}

// Round 7
// 102.554 us; speedup vs baseline: 17.8715x; 1.1270x over previous
//
#include <hip/hip_runtime.h>

// SoftFAPELoss: B=8, N=M=4096, D=3. Exact two-pass shifted softmax.
// softfape_main: grid 1024 x 512 thr (8 waves). Block = (b, 256-row group,
//   1/8th of M = 512 q). q's transformed+prescaled into 8 KB LDS
//   (q.xyz = -2c*y, q.w = c*|y|^2); wave scans a 64-q slice via wave-uniform
//   ds_read_b128 broadcast; lane owns 4 rows.
//   Pass 1 (4 VALU/pair): A = q.p + c|q|^2 (3 fma), minA = min(minA, A).
//     Block merge of minA across 8 waves -> uniform per-row shift sh.
//   Pass 2 (6 VALU + 1 exp/pair): arg = sh - A <= 0, w = exp2(arg),
//     L += w, SA = fma(w, arg, SA). Chunk-min term -> w = 1, so L >= 1:
//     underflow structurally impossible. Plain adds merge the 8 waves
//     (same shift). Chunk partial (m_d = sh + pw, L, SA) -> Pg.
// softfape_finalize: merge 8 chunk partials per row with exp2(m - m_i) <= 1
//   factors; wd = m - SA/L; block-reduce; atomicAdd * T*ln2/(B*N).

#define B_    8
#define N_    4096
#define M_    4096
#define NWAVE 8
#define BLOCK (NWAVE * 64)        // 512
#define ROWS  256                 // rows per block (4 per lane)
#define MSPL  8                   // M split across blocks
#define QCH   (M_ / MSPL)         // 512 q per block
#define WQ    (QCH / NWAVE)       // 64 q per wave
#define LOG2E 1.4426950408889634f
#define LN2   0.6931471805599453f
#define BIGF  3.0e38f

__global__ __launch_bounds__(BLOCK, 8) void softfape_main(
    const float* __restrict__ X_pred, const float* __restrict__ X_true,
    const float* __restrict__ R_pred, const float* __restrict__ t_pred,
    const float* __restrict__ R_true, const float* __restrict__ t_true,
    const float* __restrict__ temp,
    float4* __restrict__ Pg)
{
    __shared__ float4 Q[QCH];            // 8 KB
    __shared__ float  Mp[NWAVE][ROWS];   // 8 KB (reused as L-partials later? kept separate)
    __shared__ float  Lp[NWAVE][ROWS];   // 8 KB
    __shared__ float  Sp[NWAVE][ROWS];   // 8 KB
    __shared__ float  shl[ROWS];         // 1 KB (uniform shift per row)
    __shared__ float  pwl[ROWS];         // 1 KB (c*|p|^2 per row)

    const int tid  = threadIdx.x;
    const int wave = tid >> 6;
    const int lane = tid & 63;
    const int x    = blockIdx.x;
    const int ms   = x & 7;
    const int rg   = (x >> 3) & 15;
    const int b    = x >> 7;

    const float T   = temp[0];
    const float c   = LOG2E / T;
    const float m2c = -2.0f * c;

    // ---- stage 512 transformed+prescaled q's (threads 0..255, 2 each) ----
    if (tid < QCH / 2) {
        const float g00 = R_true[b*9+0], g01 = R_true[b*9+1], g02 = R_true[b*9+2];
        const float g10 = R_true[b*9+3], g11 = R_true[b*9+4], g12 = R_true[b*9+5];
        const float g20 = R_true[b*9+6], g21 = R_true[b*9+7], g22 = R_true[b*9+8];
        const float u0  = t_true[b*3+0], u1 = t_true[b*3+1], u2 = t_true[b*3+2];
        const float2* xt = (const float2*)(X_true + ((size_t)b * M_ + ms * QCH) * 3);
        const float2 f0 = xt[3*tid+0], f1 = xt[3*tid+1], f2 = xt[3*tid+2];
        {
            const float y0 = fmaf(g00, f0.x, fmaf(g01, f0.y, fmaf(g02, f1.x, u0)));
            const float y1 = fmaf(g10, f0.x, fmaf(g11, f0.y, fmaf(g12, f1.x, u1)));
            const float y2 = fmaf(g20, f0.x, fmaf(g21, f0.y, fmaf(g22, f1.x, u2)));
            const float nn = fmaf(y0, y0, fmaf(y1, y1, y2 * y2));
            Q[2*tid]   = make_float4(m2c*y0, m2c*y1, m2c*y2, c*nn);
        }
        {
            const float y0 = fmaf(g00, f1.y, fmaf(g01, f2.x, fmaf(g02, f2.y, u0)));
            const float y1 = fmaf(g10, f1.y, fmaf(g11, f2.x, fmaf(g12, f2.y, u1)));
            const float y2 = fmaf(g20, f1.y, fmaf(g21, f2.x, fmaf(g22, f2.y, u2)));
            const float nn = fmaf(y0, y0, fmaf(y1, y1, y2 * y2));
            Q[2*tid+1] = make_float4(m2c*y0, m2c*y1, m2c*y2, c*nn);
        }
    }

    // ---- my 4 rows: transformed pred points, pw = c*|p|^2 ----
    float px[4], py[4], pz[4], pw[4];
    {
        const float h00 = R_pred[b*9+0], h01 = R_pred[b*9+1], h02 = R_pred[b*9+2];
        const float h10 = R_pred[b*9+3], h11 = R_pred[b*9+4], h12 = R_pred[b*9+5];
        const float h20 = R_pred[b*9+6], h21 = R_pred[b*9+7], h22 = R_pred[b*9+8];
        const float v0 = t_pred[b*3+0], v1 = t_pred[b*3+1], v2 = t_pred[b*3+2];
        const float4* xp = (const float4*)(X_pred + ((size_t)b * N_ + rg * ROWS + lane * 4) * 3);
        const float4 a0 = xp[0], a1 = xp[1], a2 = xp[2];
        const float rx[4] = {a0.x, a0.w, a1.z, a2.y};
        const float ry[4] = {a0.y, a1.x, a1.w, a2.z};
        const float rz[4] = {a0.z, a1.y, a2.x, a2.w};
        #pragma unroll
        for (int r = 0; r < 4; ++r) {
            px[r] = fmaf(h00, rx[r], fmaf(h01, ry[r], fmaf(h02, rz[r], v0)));
            py[r] = fmaf(h10, rx[r], fmaf(h11, ry[r], fmaf(h12, rz[r], v1)));
            pz[r] = fmaf(h20, rx[r], fmaf(h21, ry[r], fmaf(h22, rz[r], v2)));
            pw[r] = c * fmaf(px[r], px[r], fmaf(py[r], py[r], pz[r] * pz[r]));
            pwl[4*lane + r] = pw[r];   // rows are block-redundant across waves; same value
        }
    }

    __syncthreads();

    const float4* __restrict__ Qw = Q + wave * WQ;

    // ---- pass 1: min of A over my 64-q slice (4 VALU/pair, no trans) ----
    float mA[4] = {BIGF, BIGF, BIGF, BIGF};
    #pragma unroll 8
    for (int k = 0; k < WQ; ++k) {
        const float4 q = Qw[k];   // ds_read_b128, wave-uniform broadcast
        #pragma unroll
        for (int r = 0; r < 4; ++r) {
            const float A = fmaf(q.x, px[r], fmaf(q.y, py[r], fmaf(q.z, pz[r], q.w)));
            mA[r] = fminf(mA[r], A);
        }
    }
    #pragma unroll
    for (int r = 0; r < 4; ++r) Mp[wave][4*lane + r] = mA[r];
    __syncthreads();

    // ---- block-uniform per-row shift ----
    if (tid < ROWS) {
        float m = Mp[0][tid];
        #pragma unroll
        for (int w2 = 1; w2 < NWAVE; ++w2) m = fminf(m, Mp[w2][tid]);
        shl[tid] = m;
    }
    __syncthreads();

    const float4 sh4 = *(const float4*)&shl[4*lane];
    const float sh[4] = {sh4.x, sh4.y, sh4.z, sh4.w};

    // ---- pass 2: shifted sums (6 VALU + 1 exp per pair) ----
    float L[4]  = {0.f, 0.f, 0.f, 0.f};
    float SA[4] = {0.f, 0.f, 0.f, 0.f};
    #pragma unroll 8
    for (int k = 0; k < WQ; ++k) {
        const float4 q = Qw[k];
        #pragma unroll
        for (int r = 0; r < 4; ++r) {
            const float A   = fmaf(q.x, px[r], fmaf(q.y, py[r], fmaf(q.z, pz[r], q.w)));
            const float arg = sh[r] - A;                     // <= 0
            const float w   = __builtin_amdgcn_exp2f(arg);   // chunk-min -> 1
            L[r] += w;
            SA[r] = fmaf(w, arg, SA[r]);                     // Sum w*(m_d - d)
        }
    }
    #pragma unroll
    for (int r = 0; r < 4; ++r) {
        Lp[wave][4*lane + r] = L[r];
        Sp[wave][4*lane + r] = SA[r];
    }
    __syncthreads();

    // ---- merge 8 wave-partials per row (same shift -> plain adds) ----
    if (tid < ROWS) {
        float Lr = 0.0f, Sr = 0.0f;
        #pragma unroll
        for (int w2 = 0; w2 < NWAVE; ++w2) { Lr += Lp[w2][tid]; Sr += Sp[w2][tid]; }
        const size_t row = (size_t)b * N_ + rg * ROWS + tid;
        // m_d = chunk-min of d = minA + pw (d-units); L = sum exp2(m_d - d);
        // SA = sum w*(m_d - d)
        Pg[row * MSPL + ms] = make_float4(shl[tid] + pwl[tid], Lr, Sr, 0.0f);
    }
}

__global__ __launch_bounds__(256) void softfape_finalize(
    const float4* __restrict__ Pg, const float* __restrict__ temp,
    float* __restrict__ out)
{
    __shared__ float ws4[4];
    const int tid = threadIdx.x;
    const size_t row = (size_t)blockIdx.x * 256 + tid;

    float4 P[MSPL];
    #pragma unroll
    for (int i = 0; i < MSPL; ++i) P[i] = Pg[row * MSPL + i];

    float m = P[0].x;
    #pragma unroll
    for (int i = 1; i < MSPL; ++i) m = fminf(m, P[i].x);

    float L = 0.0f, SA = 0.0f;
    #pragma unroll
    for (int i = 0; i < MSPL; ++i) {
        const float dm = m - P[i].x;                    // <= 0
        const float f  = __builtin_amdgcn_exp2f(dm);    // global-min chunk -> 1
        L  = fmaf(P[i].y, f, L);
        // SA_i in new reference: f * (SA_i + dm * L_i)
        SA = fmaf(f, fmaf(dm, P[i].y, P[i].z), SA);
    }
    float wd = m - SA / L;   // = c * weighted_distance(row); L >= 1 guaranteed

    wd += __shfl_xor(wd, 1);  wd += __shfl_xor(wd, 2);  wd += __shfl_xor(wd, 4);
    wd += __shfl_xor(wd, 8);  wd += __shfl_xor(wd, 16); wd += __shfl_xor(wd, 32);
    if ((tid & 63) == 0) ws4[tid >> 6] = wd;
    __syncthreads();
    if (tid == 0) {
        const float s = ws4[0] + ws4[1] + ws4[2] + ws4[3];
        const float scale = temp[0] * LN2 / ((float)B_ * (float)N_);  // 1/c, mean
        atomicAdd(out, s * scale);
    }
}

extern "C" void kernel_launch(void* const* d_in, const int* in_sizes, int n_in,
                              void* d_out, int out_size, void* d_ws, size_t ws_size,
                              hipStream_t stream) {
    const float* X_pred = (const float*)d_in[0];
    const float* X_true = (const float*)d_in[1];
    const float* R_pred = (const float*)d_in[2];
    const float* t_pred = (const float*)d_in[3];
    const float* R_true = (const float*)d_in[4];
    const float* t_true = (const float*)d_in[5];
    const float* temp   = (const float*)d_in[6];
    float* out = (float*)d_out;

    float4* Pg = (float4*)d_ws;   // B*N*MSPL float4 = 4 MB, fully overwritten

    hipMemsetAsync(out, 0, sizeof(float), stream);

    softfape_main<<<dim3(B_ * 16 * MSPL), BLOCK, 0, stream>>>(
        X_pred, X_true, R_pred, t_pred, R_true, t_true, temp, Pg);

    softfape_finalize<<<dim3((B_ * N_) / 256), 256, 0, stream>>>(Pg, temp, out);
}